// Round 5
// baseline (151.473 us; speedup 1.0000x reference)
//
#include <hip/hip_runtime.h>
#include <math.h>

// LineFinderLoss: B=384 independent LSAs (L x 256, L<=64) + loss.
// One wave per batch; each lane owns 4 pred columns (j = lane + 64k).
// Round 20 = R18 (proven 90.0us; R19's in-chain fusion regressed and is
// reverted) + two fixed-overhead cuts:
//  - magic-number f32->i32: fold C=2^23+2^22 into base[]; t3 lands in
//    [2^23,2^24) so bits(t3) = 0x4B400000 + q. v_cvt eliminated (was 4
//    per pop, on the qcost critical path). key = (bits<<8)+vnjcw =
//    0x40000000 + (q<<8) + vnjcw: uniform constant, ordering and
//    tie-breaks unchanged; active keys < 2^31, retired >= 2^31.
//    tmw = t - WOFF - 0x400000 keeps s_toff/min_val/shk>>8 exact.
//    NOTE: per-step ULP=1 rounding re-quantizes the cost matrix by ~1
//    quantum (2^-15 scale, same order as existing quantization error).
//  - 2x pop-loop unroll: one taken back-edge per 2 pops.
// Everything else bit-identical to R18.

#define B_ 384
#define N_ 256
#define M_ 64

typedef unsigned long long u64;
typedef unsigned int u32;

#define WOFF (1 << 20)         // key offset (q can be negative, q+WOFF>=0)
#define MAGIC 12582912.0f      // 2^23 + 2^22, folded into base[]
#define KADJ 0x400000          // (bits>>8)-domain bias from MAGIC

static __device__ __forceinline__ float readlane_f32(float x, int l) {
  return __int_as_float(__builtin_amdgcn_readlane(__float_as_int(x), l));
}

// Quantized cost bits from prescaled preds + magic-folded base.
// t3 in [2^23,2^24): raw bits = 0x4B400000 + q (q the integer cost).
// Same instruction sequence at every call site -> consistent matrix.
static __device__ __forceinline__ u32 qbits(float pxs_, float pys_, float pzs_,
                                            float base_,
                                            float lx, float ly, float lz) {
  const float t1 = __fmaf_rn(pxs_, lx, base_);
  const float t2 = __fmaf_rn(pys_, ly, t1);
  const float t3 = __fmaf_rn(pzs_, lz, t2);
  return (u32)__float_as_int(t3);
}

// Two interleaved wave-min chains + in-asm merge; result valid on lane 63.
// Each chain's step is spaced by the other chain's instruction (2 cy) —
// covers the VALU->DPP hazard. (R18 form — R19's variant regressed.)
static __device__ __forceinline__ u32 wave_min2_merge_u32(u32 a, u32 b) {
  asm("s_nop 1\n\t"
      "v_min_u32_dpp %0, %0, %0 row_shr:1 row_mask:0xf bank_mask:0xf\n\t"
      "v_min_u32_dpp %1, %1, %1 row_shr:1 row_mask:0xf bank_mask:0xf\n\t"
      "v_min_u32_dpp %0, %0, %0 row_shr:2 row_mask:0xf bank_mask:0xf\n\t"
      "v_min_u32_dpp %1, %1, %1 row_shr:2 row_mask:0xf bank_mask:0xf\n\t"
      "v_min_u32_dpp %0, %0, %0 row_shr:4 row_mask:0xf bank_mask:0xf\n\t"
      "v_min_u32_dpp %1, %1, %1 row_shr:4 row_mask:0xf bank_mask:0xf\n\t"
      "v_min_u32_dpp %0, %0, %0 row_shr:8 row_mask:0xf bank_mask:0xf\n\t"
      "v_min_u32_dpp %1, %1, %1 row_shr:8 row_mask:0xf bank_mask:0xf\n\t"
      "v_min_u32_dpp %0, %0, %0 row_bcast:15 row_mask:0xa bank_mask:0xf\n\t"
      "v_min_u32_dpp %1, %1, %1 row_bcast:15 row_mask:0xa bank_mask:0xf\n\t"
      "v_min_u32_dpp %0, %0, %0 row_bcast:31 row_mask:0xc bank_mask:0xf\n\t"
      "v_min_u32_dpp %1, %1, %1 row_bcast:31 row_mask:0xc bank_mask:0xf\n\t"
      "v_min_u32 %0, %0, %1"
      : "+v"(a), "+v"(b));
  return a;
}

__global__ __launch_bounds__(64) void lsa_loss_kernel(
    const float* __restrict__ pred,
    const float* __restrict__ label,
    const int* __restrict__ label_len,
    double* __restrict__ ws,
    float* __restrict__ out)
{
  const int b = blockIdx.x;
  const int lane = threadIdx.x;  // 0..63

  __shared__ float lab_x[M_], lab_y[M_], lab_z[M_];
  __shared__ int r4c_lds[N_];    // epilogue-only inverse map

  const float* lp = label + (size_t)(b * M_ + lane) * 3;
  const float labx = lp[0], laby = lp[1], labz = lp[2];
  lab_x[lane] = labx; lab_y[lane] = laby; lab_z[lane] = labz;

  float px[4], py[4], pz[4], pxs[4], pys[4], pzs[4];
  float lc[4], lca[4], base[4];      // base is loop-invariant (magic folded)
  u32 vnjcw[4];                      // ((vn+WOFF)<<8)|jc  (+bit31 = retired)
  u32 vnjcwB[4];                     // vnjcw | 0x80000000 (pre-biased copy)
  u32 njc[4];                        // -(lane+64k): cancels key low byte
  const float4* pred4 = reinterpret_cast<const float4*>(pred);
#pragma unroll
  for (int k = 0; k < 4; ++k) {
    const float4 p = pred4[b * N_ + lane + 64 * k];
    px[k] = p.x; py[k] = p.y; pz[k] = p.z;
    pxs[k] = __fmul_rn(p.x, -3276.8f);   // -2 * 0.05 * 2^15 prescale
    pys[k] = __fmul_rn(p.y, -3276.8f);
    pzs[k] = __fmul_rn(p.z, -3276.8f);
    lc[k]  = logf(__fadd_rn(p.w, 1e-5f));
    lca[k] = logf(__fadd_rn(__fsub_rn(1.0f, p.w), 1e-5f));
    const float qgf = __fmul_rn(__fsub_rn(lca[k], lc[k]), 32768.0f);
    const float npp = __fmaf_rn(p.z, p.z, __fmaf_rn(p.y, p.y, __fmul_rn(p.x, p.x)));
    base[k] = __fadd_rn(__fmaf_rn(npp, 1638.4f, qgf), MAGIC);
    const u32 jck = (u32)(lane + 64 * k);
    vnjcw[k]  = ((u32)WOFF << 8) | jck;
    vnjcwB[k] = vnjcw[k] | 0x80000000u;
    njc[k]    = (u32)(0u - jck);
  }
  int c4r = -1;   // col4row[lane]
  int u_reg = 0;  // u[lane]

  int L = label_len[b];
  L = (L < 1) ? 1 : ((L > M_) ? M_ : L);

  __syncthreads();  // labels visible (epilogue gather)

  // ---- Warm start: u_i = min_j Q_ij, greedy claim of argmin columns ----
  // key = (qbits<<8) + vnjcw = 0x40000000 + ((q+WOFF)<<8)|jc.
  for (int r = 0; r < L; ++r) {
    const float lx = readlane_f32(labx, r);
    const float ly = readlane_f32(laby, r);
    const float lz = readlane_f32(labz, r);
    u32 cand[4];
#pragma unroll
    for (int k = 0; k < 4; ++k) {
      const u32 qb = qbits(pxs[k], pys[k], pzs[k], base[k], lx, ly, lz);
      cand[k] = (qb << 8) + vnjcw[k];          // v_lshl_add_u32
    }
    u32 ca = (cand[0] < cand[1]) ? cand[0] : cand[1];
    u32 cb = (cand[2] < cand[3]) ? cand[2] : cand[3];
    const u32 wk = (u32)__builtin_amdgcn_readlane(
        (int)wave_min2_merge_u32(ca, cb), 63);
    const int j1 = (int)(wk & 0xFF);
    if (lane == r) u_reg = (int)((wk >> 8) & 0x7FFFFF) - WOFF - KADJ + 
                           ((int)(wk >> 8) & ~0x7FFFFF & 0);  // see note
    // note: wk>>8 = 0x400000 + q + WOFF exactly (bounded < 2^23), so the
    // plain form is fine:
    if (lane == r) u_reg = (int)(wk >> 8) - WOFF - KADJ;
    const bool taken = __ballot(c4r == j1) != 0ull;
    if (!taken && lane == r) c4r = j1;
  }
  u64 free_mask = __ballot((lane < L) && (c4r < 0));

  // ---- Greedy-walk SSP for free rows ----
  while (free_mask) {
    const int cur_row = (int)__builtin_ctzll(free_mask);
    free_mask &= free_mask - 1;

    u32 shk[4] = {0x7FFFFFFFu, 0x7FFFFFFFu, 0x7FFFFFFFu, 0x7FFFFFFFu};
    int mvj = 0, joined = 0, min_val = 0;
    int i_cur = cur_row;
    int u_i = __builtin_amdgcn_readlane(u_reg, i_cur);
    float lx = readlane_f32(labx, i_cur);
    float ly = readlane_f32(laby, i_cur);
    float lz = readlane_f32(labz, i_cur);
    int t = 0 - u_i;
    int sink = -1;

    // One pop. key = 0x40000000 + ((q+vn+WOFF)<<8) + jc;
    // tmw = t-WOFF-KADJ makes min_val = (wk>>8)+tmw = q+vn+t = dd, and
    // s_toff = (tmw<<8)+i_cur makes skey = key+njc+s_toff = (dd<<8)|i_cur
    // (the 0x40000000 cancels against tmw's -KADJ<<8). Exact integers.
#define POP_ITER()                                                          \
    {                                                                       \
      const int tmw = t - WOFF - KADJ;                                      \
      const u32 s_toff = ((u32)tmw << 8) + (u32)i_cur;                      \
      u32 key[4];                                                           \
      _Pragma("unroll")                                                     \
      for (int k = 0; k < 4; ++k) {                                         \
        const u32 qb = qbits(pxs[k], pys[k], pzs[k], base[k], lx, ly, lz);  \
        key[k] = (qb << 8) + vnjcw[k];                                      \
      }                                                                     \
      u32 ca = (key[0] < key[1]) ? key[0] : key[1];                         \
      u32 cb = (key[2] < key[3]) ? key[2] : key[3];                         \
      u32 m = wave_min2_merge_u32(ca, cb);                                  \
      _Pragma("unroll")                                                     \
      for (int k = 0; k < 4; ++k) {                                         \
        const u32 skey = key[k] + njc[k] + s_toff;                          \
        shk[k] = (skey < shk[k]) ? skey : shk[k];                           \
      }                                                                     \
      const u32 wk = (u32)__builtin_amdgcn_readlane((int)m, 63);            \
      const int j_min = (int)(wk & 0xFF);                                   \
      min_val = (int)(wk >> 8) + tmw;                                       \
      const int kk = j_min >> 6;                                            \
      const bool selfc = (lane == (j_min & 63));                            \
      vnjcw[0] = (selfc && kk == 0) ? vnjcwB[0] : vnjcw[0];                 \
      vnjcw[1] = (selfc && kk == 1) ? vnjcwB[1] : vnjcw[1];                 \
      vnjcw[2] = (selfc && kk == 2) ? vnjcwB[2] : vnjcw[2];                 \
      vnjcw[3] = (selfc && kk == 3) ? vnjcwB[3] : vnjcw[3];                 \
      const bool own = (c4r == j_min);                                      \
      const u64 om = __ballot(own);                                         \
      if (om == 0ull) { sink = j_min; break; }                              \
      i_cur = (int)__builtin_ctzll(om);                                     \
      if (own) { mvj = min_val; joined = 1; }                               \
      u_i = __builtin_amdgcn_readlane(u_reg, i_cur);                        \
      lx = readlane_f32(labx, i_cur);                                       \
      ly = readlane_f32(laby, i_cur);                                       \
      lz = readlane_f32(labz, i_cur);                                       \
      t = min_val - u_i;                                                    \
    }

    while (true) {      // 2x unrolled: one taken back-edge per 2 pops
      POP_ITER()
      POP_ITER()
    }
#undef POP_ITER

    // Dual updates. Retired (popped) columns = bit31 set. For each:
    // vn += min_val - dd_min (dd_min = shk>>8, true d at its minimum);
    // applied as Delta<<8 so the low jc byte is preserved; bit31 cleared.
    if (lane == cur_row)  u_reg += min_val;
    else if (joined)      u_reg += min_val - mvj;
#pragma unroll
    for (int k = 0; k < 4; ++k) {
      if ((int)vnjcw[k] < 0) {
        const int ddk = (int)(shk[k] >> 8);
        vnjcw[k] = (vnjcw[k] & 0x7FFFFFFFu) + ((u32)(min_val - ddk) << 8);
      }
      vnjcwB[k] = vnjcw[k] | 0x80000000u;   // refresh biased copy
    }

    // Augment: lockstep walk; prev row = low byte of shk.
    {
      int j = sink;
      while (true) {
        const int kkj = j >> 6, lj = j & 63;
        const int s0 = __builtin_amdgcn_readlane((int)shk[0], lj);
        const int s1 = __builtin_amdgcn_readlane((int)shk[1], lj);
        const int s2 = __builtin_amdgcn_readlane((int)shk[2], lj);
        const int s3 = __builtin_amdgcn_readlane((int)shk[3], lj);
        const int ps = (kkj == 0) ? s0 : (kkj == 1) ? s1 : (kkj == 2) ? s2 : s3;
        const int ii = ps & 0xFF;
        const int jn = __builtin_amdgcn_readlane(c4r, ii);
        if (lane == ii) c4r = j;
        if (ii == cur_row) break;
        j = jn;
      }
    }
  }

  // ---- Epilogue: rebuild row4col once via LDS inverse of c4r ----
#pragma unroll
  for (int k = 0; k < 4; ++k) r4c_lds[lane + 64 * k] = -1;
  __syncthreads();
  if (c4r >= 0) r4c_lds[c4r] = lane;
  __syncthreads();

  double loc = 0.0, cpos = 0.0, cneg = 0.0;
#pragma unroll
  for (int k = 0; k < 4; ++k) {
    const int l = r4c_lds[lane + 64 * k];
    if (l >= 0) {
      const float d0 = __fsub_rn(px[k], lab_x[l]);
      const float d1 = __fsub_rn(py[k], lab_y[l]);
      const float d2 = __fsub_rn(pz[k], lab_z[l]);
      const float nd = __fadd_rn(__fadd_rn(__fmul_rn(d0, d0), __fmul_rn(d1, d1)),
                                 __fmul_rn(d2, d2));
      loc += (double)nd;
      cpos -= (double)lc[k];
    } else {
      cneg -= (double)lca[k];
    }
  }
  for (int off = 32; off >= 1; off >>= 1) {
    loc += __shfl_xor(loc, off, 64);
    cpos += __shfl_xor(cpos, off, 64);
    cneg += __shfl_xor(cneg, off, 64);
  }

  // ---- Fused finalization via device-scope atomics + ticket counter ----
  if (lane == 0) {
    atomicAdd(&ws[0], loc);
    atomicAdd(&ws[1], cpos + cneg + 1e-4);
    if (b == B_ - 1) { atomicAdd(&ws[2], cpos); atomicAdd(&ws[3], cneg); }
    __threadfence();
    unsigned int* cnt = (unsigned int*)(ws + 4);
    const unsigned int old = atomicAdd(cnt, 1u);
    if (old == (unsigned int)(B_ - 1)) {
      __threadfence();
      const double loc_t  = atomicAdd(&ws[0], 0.0);
      const double conf_t = atomicAdd(&ws[1], 0.0);
      const double cpos_l = atomicAdd(&ws[2], 0.0);
      const double cneg_l = atomicAdd(&ws[3], 0.0);
      const double lloc = 0.1 * (loc_t * 0.5);  // ALPHA * location_loss
      out[0] = (float)(lloc + conf_t);
      out[1] = (float)lloc;
      out[2] = (float)cpos_l;
      out[3] = (float)cneg_l;
    }
  }
}

extern "C" void kernel_launch(void* const* d_in, const int* in_sizes, int n_in,
                              void* d_out, int out_size, void* d_ws, size_t ws_size,
                              hipStream_t stream) {
  const float* pred = (const float*)d_in[0];       // (B, N, 4) fp32
  const float* label = (const float*)d_in[1];      // (B, M, 3) fp32
  const int* label_len = (const int*)d_in[2];      // (B,) int32
  double* ws = (double*)d_ws;
  float* out = (float*)d_out;

  hipMemsetAsync(d_ws, 0, 64, stream);  // 4 f64 accumulators + ticket
  lsa_loss_kernel<<<B_, 64, 0, stream>>>(pred, label, label_len, ws, out);
}

// Round 6
// 145.179 us; speedup vs baseline: 1.0434x; 1.0434x over previous
//
#include <hip/hip_runtime.h>
#include <math.h>

// LineFinderLoss: B=384 independent LSAs (L x 256, L<=64) + loss.
// One wave per batch; each lane owns 4 pred columns (j = lane + 64k).
// Round 21 = R18 (proven 90.0us; R19 fusion and R20 magic/unroll both
// regressed and are reverted) + forced packed-fp32 qcost:
//  - 6x v_pk_fma_f32 via inline asm (R17's intrinsic form scalarized)
//    replaces 12x v_fma_f32: -12 cy issue per pop. Labels broadcast as
//    SGPR pairs built by SALU (co-issued, ~free); VOP3P takes the one
//    scalar source. Per-element rounding is IEEE-identical to v_fma_f32,
//    same operand order, same base -> cost matrix / pops / duals are
//    BIT-IDENTICAL to R18: absmax must stay exactly 121.5.
// Evidence base: ~127 cy/pop = ~95 issue + ~25 tail latency (R19's +3us
// matched pure issue cost of +2 instrs -> DPP hazards already covered).

#define B_ 384
#define N_ 256
#define M_ 64

typedef unsigned long long u64;
typedef unsigned int u32;
typedef float v2f __attribute__((ext_vector_type(2)));

#define WOFF (1 << 20)         // key offset (q can be negative, q+WOFF>=0)

// Pack a wave-uniform 32-bit value into both halves of an SGPR pair.
static __device__ __forceinline__ u64 pack2(int bits) {
  return ((u64)(u32)bits << 32) | (u32)bits;
}

// Packed quantized cost: one v_pk_fma_f32 chain covers two columns.
// d = src0*src1 + src2 per 32-bit half; rounding identical to v_fma_f32.
static __device__ __forceinline__ v2f qcost2pk(v2f pxs, v2f pys, v2f pzs,
                                               v2f base,
                                               u64 lxp, u64 lyp, u64 lzp) {
  v2f acc = base;
  asm("v_pk_fma_f32 %0, %1, %4, %0\n\t"
      "v_pk_fma_f32 %0, %2, %5, %0\n\t"
      "v_pk_fma_f32 %0, %3, %6, %0"
      : "+v"(acc)
      : "v"(pxs), "v"(pys), "v"(pzs), "s"(lxp), "s"(lyp), "s"(lzp));
  return acc;
}

// Two interleaved wave-min chains + in-asm merge; result valid on lane 63.
// Each chain's step is spaced by the other chain's instruction (2 cy) —
// covers the VALU->DPP hazard. (R18 form — R19's variant regressed.)
static __device__ __forceinline__ u32 wave_min2_merge_u32(u32 a, u32 b) {
  asm("s_nop 1\n\t"
      "v_min_u32_dpp %0, %0, %0 row_shr:1 row_mask:0xf bank_mask:0xf\n\t"
      "v_min_u32_dpp %1, %1, %1 row_shr:1 row_mask:0xf bank_mask:0xf\n\t"
      "v_min_u32_dpp %0, %0, %0 row_shr:2 row_mask:0xf bank_mask:0xf\n\t"
      "v_min_u32_dpp %1, %1, %1 row_shr:2 row_mask:0xf bank_mask:0xf\n\t"
      "v_min_u32_dpp %0, %0, %0 row_shr:4 row_mask:0xf bank_mask:0xf\n\t"
      "v_min_u32_dpp %1, %1, %1 row_shr:4 row_mask:0xf bank_mask:0xf\n\t"
      "v_min_u32_dpp %0, %0, %0 row_shr:8 row_mask:0xf bank_mask:0xf\n\t"
      "v_min_u32_dpp %1, %1, %1 row_shr:8 row_mask:0xf bank_mask:0xf\n\t"
      "v_min_u32_dpp %0, %0, %0 row_bcast:15 row_mask:0xa bank_mask:0xf\n\t"
      "v_min_u32_dpp %1, %1, %1 row_bcast:15 row_mask:0xa bank_mask:0xf\n\t"
      "v_min_u32_dpp %0, %0, %0 row_bcast:31 row_mask:0xc bank_mask:0xf\n\t"
      "v_min_u32_dpp %1, %1, %1 row_bcast:31 row_mask:0xc bank_mask:0xf\n\t"
      "v_min_u32 %0, %0, %1"
      : "+v"(a), "+v"(b));
  return a;
}

__global__ __launch_bounds__(64) void lsa_loss_kernel(
    const float* __restrict__ pred,
    const float* __restrict__ label,
    const int* __restrict__ label_len,
    double* __restrict__ ws,
    float* __restrict__ out)
{
  const int b = blockIdx.x;
  const int lane = threadIdx.x;  // 0..63

  __shared__ float lab_x[M_], lab_y[M_], lab_z[M_];
  __shared__ int r4c_lds[N_];    // epilogue-only inverse map

  const float* lp = label + (size_t)(b * M_ + lane) * 3;
  const float labx = lp[0], laby = lp[1], labz = lp[2];
  lab_x[lane] = labx; lab_y[lane] = laby; lab_z[lane] = labz;

  float px[4], py[4], pz[4], lc[4], lca[4];
  v2f pxs2[2], pys2[2], pzs2[2], base2[2];   // column pairs (k = 2p+h)
  u32 vnjcw[4];                      // ((vn+WOFF)<<8)|jc  (+bit31 = retired)
  u32 vnjcwB[4];                     // vnjcw | 0x80000000 (pre-biased copy)
  u32 njc[4];                        // -(lane+64k): cancels key low byte
  const float4* pred4 = reinterpret_cast<const float4*>(pred);
#pragma unroll
  for (int p = 0; p < 2; ++p) {
#pragma unroll
    for (int h = 0; h < 2; ++h) {
      const int k = 2 * p + h;
      const float4 q = pred4[b * N_ + lane + 64 * k];
      px[k] = q.x; py[k] = q.y; pz[k] = q.z;
      pxs2[p][h] = __fmul_rn(q.x, -3276.8f);   // -2 * 0.05 * 2^15 prescale
      pys2[p][h] = __fmul_rn(q.y, -3276.8f);
      pzs2[p][h] = __fmul_rn(q.z, -3276.8f);
      lc[k]  = logf(__fadd_rn(q.w, 1e-5f));
      lca[k] = logf(__fadd_rn(__fsub_rn(1.0f, q.w), 1e-5f));
      const float qgf = __fmul_rn(__fsub_rn(lca[k], lc[k]), 32768.0f);
      const float npp = __fmaf_rn(q.z, q.z, __fmaf_rn(q.y, q.y, __fmul_rn(q.x, q.x)));
      base2[p][h] = __fmaf_rn(npp, 1638.4f, qgf);
      const u32 jck = (u32)(lane + 64 * k);
      vnjcw[k]  = ((u32)WOFF << 8) | jck;
      vnjcwB[k] = vnjcw[k] | 0x80000000u;
      njc[k]    = (u32)(0u - jck);
    }
  }
  int c4r = -1;   // col4row[lane]
  int u_reg = 0;  // u[lane]

  int L = label_len[b];
  L = (L < 1) ? 1 : ((L > M_) ? M_ : L);

  __syncthreads();  // labels visible (epilogue gather)

  // ---- Warm start: u_i = min_j Q_ij, greedy claim of argmin columns ----
  for (int r = 0; r < L; ++r) {
    const u64 lxp = pack2(__builtin_amdgcn_readlane(__float_as_int(labx), r));
    const u64 lyp = pack2(__builtin_amdgcn_readlane(__float_as_int(laby), r));
    const u64 lzp = pack2(__builtin_amdgcn_readlane(__float_as_int(labz), r));
    const v2f t3a = qcost2pk(pxs2[0], pys2[0], pzs2[0], base2[0], lxp, lyp, lzp);
    const v2f t3b = qcost2pk(pxs2[1], pys2[1], pzs2[1], base2[1], lxp, lyp, lzp);
    u32 cand[4];
    cand[0] = (((u32)(int)t3a[0]) << 8) + vnjcw[0];    // v_lshl_add_u32
    cand[1] = (((u32)(int)t3a[1]) << 8) + vnjcw[1];
    cand[2] = (((u32)(int)t3b[0]) << 8) + vnjcw[2];
    cand[3] = (((u32)(int)t3b[1]) << 8) + vnjcw[3];
    u32 ca = (cand[0] < cand[1]) ? cand[0] : cand[1];
    u32 cb = (cand[2] < cand[3]) ? cand[2] : cand[3];
    const u32 wk = (u32)__builtin_amdgcn_readlane(
        (int)wave_min2_merge_u32(ca, cb), 63);
    const int j1 = (int)(wk & 0xFF);
    if (lane == r) u_reg = (int)(wk >> 8) - WOFF;
    const bool taken = __ballot(c4r == j1) != 0ull;
    if (!taken && lane == r) c4r = j1;
  }
  u64 free_mask = __ballot((lane < L) && (c4r < 0));

  // ---- Greedy-walk SSP for free rows ----
  while (free_mask) {
    const int cur_row = (int)__builtin_ctzll(free_mask);
    free_mask &= free_mask - 1;

    u32 shk[4] = {0x7FFFFFFFu, 0x7FFFFFFFu, 0x7FFFFFFFu, 0x7FFFFFFFu};
    int mvj = 0, joined = 0, min_val = 0;
    int i_cur = cur_row;
    int u_i = __builtin_amdgcn_readlane(u_reg, i_cur);
    u64 lxp = pack2(__builtin_amdgcn_readlane(__float_as_int(labx), i_cur));
    u64 lyp = pack2(__builtin_amdgcn_readlane(__float_as_int(laby), i_cur));
    u64 lzp = pack2(__builtin_amdgcn_readlane(__float_as_int(labz), i_cur));
    int t = 0 - u_i;
    int sink = -1;

    while (true) {
      // SALU-uniform helpers for this pop.
      const int tmw = t - WOFF;                          // s_sub
      const u32 s_toff = ((u32)tmw << 8) + (u32)i_cur;   // s_lshl + s_add
      const v2f t3a = qcost2pk(pxs2[0], pys2[0], pzs2[0], base2[0],
                               lxp, lyp, lzp);
      const v2f t3b = qcost2pk(pxs2[1], pys2[1], pzs2[1], base2[1],
                               lxp, lyp, lzp);
      u32 key[4];
      key[0] = (((u32)(int)t3a[0]) << 8) + vnjcw[0];   // v_lshl_add_u32
      key[1] = (((u32)(int)t3a[1]) << 8) + vnjcw[1];
      key[2] = (((u32)(int)t3b[0]) << 8) + vnjcw[2];
      key[3] = (((u32)(int)t3b[1]) << 8) + vnjcw[3];
      u32 ca = (key[0] < key[1]) ? key[0] : key[1];
      u32 cb = (key[2] < key[3]) ? key[2] : key[3];
      u32 m = wave_min2_merge_u32(ca, cb);
      // shk update issues in the DPP->readlane shadow (no dep on m).
      // skey = ((q+vn+t)<<8)|i_cur : key's low byte is exactly jc, njc
      // cancels it, s_toff adds (t-WOFF)<<8 and i_cur. Exact integer alg.
#pragma unroll
      for (int k = 0; k < 4; ++k) {
        const u32 skey = key[k] + njc[k] + s_toff;       // v_add3_u32
        shk[k] = (skey < shk[k]) ? skey : shk[k];
      }
      const u32 wk = (u32)__builtin_amdgcn_readlane((int)m, 63);
      const int j_min = (int)(wk & 0xFF);
      min_val = (int)(wk >> 8) + tmw;                    // SALU recover
      const int kk = j_min >> 6;
      const bool selfc = (lane == (j_min & 63));
      // Retire popped column: set bit31 via pre-biased copy (1 cndmask/k).
      vnjcw[0] = (selfc && kk == 0) ? vnjcwB[0] : vnjcw[0];
      vnjcw[1] = (selfc && kk == 1) ? vnjcwB[1] : vnjcw[1];
      vnjcw[2] = (selfc && kk == 2) ? vnjcwB[2] : vnjcw[2];
      vnjcw[3] = (selfc && kk == 3) ? vnjcwB[3] : vnjcw[3];
      // Owner row via the inverse map held in c4r.
      const bool own = (c4r == j_min);
      const u64 om = __ballot(own);
      if (om == 0ull) { sink = j_min; break; }
      i_cur = (int)__builtin_ctzll(om);
      if (own) { mvj = min_val; joined = 1; }
      u_i = __builtin_amdgcn_readlane(u_reg, i_cur);
      lxp = pack2(__builtin_amdgcn_readlane(__float_as_int(labx), i_cur));
      lyp = pack2(__builtin_amdgcn_readlane(__float_as_int(laby), i_cur));
      lzp = pack2(__builtin_amdgcn_readlane(__float_as_int(labz), i_cur));
      t = min_val - u_i;
    }

    // Dual updates. Retired (popped) columns = bit31 set. For each:
    // vn += min_val - dd_min (dd_min = shk>>8, true d at its minimum);
    // applied as Delta<<8 so the low jc byte is preserved; bit31 cleared.
    if (lane == cur_row)  u_reg += min_val;
    else if (joined)      u_reg += min_val - mvj;
#pragma unroll
    for (int k = 0; k < 4; ++k) {
      if ((int)vnjcw[k] < 0) {
        const int ddk = (int)(shk[k] >> 8);
        vnjcw[k] = (vnjcw[k] & 0x7FFFFFFFu) + ((u32)(min_val - ddk) << 8);
      }
      vnjcwB[k] = vnjcw[k] | 0x80000000u;   // refresh biased copy
    }

    // Augment: lockstep walk; prev row = low byte of shk.
    {
      int j = sink;
      while (true) {
        const int kkj = j >> 6, lj = j & 63;
        const int s0 = __builtin_amdgcn_readlane((int)shk[0], lj);
        const int s1 = __builtin_amdgcn_readlane((int)shk[1], lj);
        const int s2 = __builtin_amdgcn_readlane((int)shk[2], lj);
        const int s3 = __builtin_amdgcn_readlane((int)shk[3], lj);
        const int ps = (kkj == 0) ? s0 : (kkj == 1) ? s1 : (kkj == 2) ? s2 : s3;
        const int ii = ps & 0xFF;
        const int jn = __builtin_amdgcn_readlane(c4r, ii);
        if (lane == ii) c4r = j;
        if (ii == cur_row) break;
        j = jn;
      }
    }
  }

  // ---- Epilogue: rebuild row4col once via LDS inverse of c4r ----
#pragma unroll
  for (int k = 0; k < 4; ++k) r4c_lds[lane + 64 * k] = -1;
  __syncthreads();
  if (c4r >= 0) r4c_lds[c4r] = lane;
  __syncthreads();

  double loc = 0.0, cpos = 0.0, cneg = 0.0;
#pragma unroll
  for (int k = 0; k < 4; ++k) {
    const int l = r4c_lds[lane + 64 * k];
    if (l >= 0) {
      const float d0 = __fsub_rn(px[k], lab_x[l]);
      const float d1 = __fsub_rn(py[k], lab_y[l]);
      const float d2 = __fsub_rn(pz[k], lab_z[l]);
      const float nd = __fadd_rn(__fadd_rn(__fmul_rn(d0, d0), __fmul_rn(d1, d1)),
                                 __fmul_rn(d2, d2));
      loc += (double)nd;
      cpos -= (double)lc[k];
    } else {
      cneg -= (double)lca[k];
    }
  }
  for (int off = 32; off >= 1; off >>= 1) {
    loc += __shfl_xor(loc, off, 64);
    cpos += __shfl_xor(cpos, off, 64);
    cneg += __shfl_xor(cneg, off, 64);
  }

  // ---- Fused finalization via device-scope atomics + ticket counter ----
  if (lane == 0) {
    atomicAdd(&ws[0], loc);
    atomicAdd(&ws[1], cpos + cneg + 1e-4);
    if (b == B_ - 1) { atomicAdd(&ws[2], cpos); atomicAdd(&ws[3], cneg); }
    __threadfence();
    unsigned int* cnt = (unsigned int*)(ws + 4);
    const unsigned int old = atomicAdd(cnt, 1u);
    if (old == (unsigned int)(B_ - 1)) {
      __threadfence();
      const double loc_t  = atomicAdd(&ws[0], 0.0);
      const double conf_t = atomicAdd(&ws[1], 0.0);
      const double cpos_l = atomicAdd(&ws[2], 0.0);
      const double cneg_l = atomicAdd(&ws[3], 0.0);
      const double lloc = 0.1 * (loc_t * 0.5);  // ALPHA * location_loss
      out[0] = (float)(lloc + conf_t);
      out[1] = (float)lloc;
      out[2] = (float)cpos_l;
      out[3] = (float)cneg_l;
    }
  }
}

extern "C" void kernel_launch(void* const* d_in, const int* in_sizes, int n_in,
                              void* d_out, int out_size, void* d_ws, size_t ws_size,
                              hipStream_t stream) {
  const float* pred = (const float*)d_in[0];       // (B, N, 4) fp32
  const float* label = (const float*)d_in[1];      // (B, M, 3) fp32
  const int* label_len = (const int*)d_in[2];      // (B,) int32
  double* ws = (double*)d_ws;
  float* out = (float*)d_out;

  hipMemsetAsync(d_ws, 0, 64, stream);  // 4 f64 accumulators + ticket
  lsa_loss_kernel<<<B_, 64, 0, stream>>>(pred, label, label_len, ws, out);
}